// Round 6
// baseline (1762.060 us; speedup 1.0000x reference)
//
#include <hip/hip_runtime.h>
#include <math.h>

#define B_ 64
#define T_ 1024
#define I_ 128
#define H_ 512

typedef _Float16 h2_t __attribute__((ext_vector_type(2)));
union U32H2 { unsigned u; h2_t h; };

__device__ __forceinline__ float fdot2u(unsigned a, unsigned b, float c) {
    U32H2 ua, ub; ua.u = a; ub.u = b;
    return __builtin_amdgcn_fdot2(ua.h, ub.h, c, false);
}
__device__ __forceinline__ unsigned packh2(float x, float y) {
    U32H2 r; r.h.x = (_Float16)x; r.h.y = (_Float16)y; return r.u;
}

// ---------------- prep: pack fp16 weight layouts for the 1024-thread rnn -----
// rnn map: c=tid>>7 (8 k-slices of 32 h2-words), g=tid&127 (outputs 4g..4g+3).
// Reg part  (m=0..23):  wpack uint4[(r*6+q)*1024 + tid], comp r4 = word m=4q+r4
//                       = half2 W[4g+r][2w..2w+1], w = 32c + m.
// LDS part  (m'=0..7):  wldsg uint4[c*1024 + m'*128 + g], comp r
//                       = half2 W[4g+r][2w..2w+1], w = 32c + 24 + m'.
// wih2[(i2<<9)+h] = half2 Wih[h][2i2..2i2+1];  biasv[h] = b_ih[h]+b_hh[h].
__global__ void prep(const float* __restrict__ wih, const float* __restrict__ whh,
                     const float* __restrict__ bih, const float* __restrict__ bhh,
                     unsigned* __restrict__ wpack, unsigned* __restrict__ wldsg,
                     unsigned* __restrict__ wih2, float* __restrict__ biasv) {
    int e = blockIdx.x * 256 + threadIdx.x;
    if (e < 98304) {
        int u4 = e >> 2, r4 = e & 3;
        int qr = u4 >> 10, tid = u4 & 1023;
        int r = qr / 6, q = qr % 6;
        int m = (q << 2) + r4;
        int c = tid >> 7, g = tid & 127;
        int j = (g << 2) + r;
        int w = (c << 5) + m;
        wpack[e] = packh2(whh[j * H_ + 2 * w], whh[j * H_ + 2 * w + 1]);
    }
    if (e < 32768) {
        int u = e >> 2, r = e & 3;
        int c = u >> 10, mp = (u >> 7) & 7, g = u & 127;
        int j = (g << 2) + r;
        int w = (c << 5) + 24 + mp;
        wldsg[e] = packh2(whh[j * H_ + 2 * w], whh[j * H_ + 2 * w + 1]);
    }
    if (e < 64 * 512) {
        int i2 = e >> 9, h = e & 511;
        wih2[e] = packh2(wih[h * I_ + (i2 << 1)], wih[h * I_ + (i2 << 1) + 1]);
    }
    if (e < H_) biasv[e] = bih[e] + bhh[e];
}

// ---------------- xp = x @ W_ih^T + biases, fp16 [B][T][H] (unchanged) --------
__global__ __launch_bounds__(512, 2) void xp_gemm(
    const float* __restrict__ x, const unsigned* __restrict__ wih2,
    const float* __restrict__ biasv, _Float16* __restrict__ xph) {
    __shared__ unsigned w2[64 * 512];
    __shared__ unsigned x2[32 * 64];
    const int tid = threadIdx.x, b = blockIdx.x, t0 = blockIdx.y * 32;

    #pragma unroll
    for (int q = 0; q < 64; ++q) w2[tid + (q << 9)] = wih2[tid + (q << 9)];
    #pragma unroll
    for (int q = 0; q < 4; ++q) {
        int idx = tid * 4 + q;
        int t = idx >> 6, i2 = idx & 63;
        const float2 xv = *(const float2*)(x + ((size_t)b * T_ + t0 + t) * I_ + (i2 << 1));
        x2[idx] = packh2(xv.x, xv.y);
    }
    __syncthreads();
    const float bias = biasv[tid];
    for (int t = 0; t < 32; ++t) {
        float acc = bias;
        #pragma unroll
        for (int i2 = 0; i2 < 64; ++i2)
            acc = fdot2u(x2[(t << 6) + i2], w2[(i2 << 9) + tid], acc);
        xph[((size_t)b * T_ + t0 + t) * H_ + tid] = (_Float16)acc;
    }
}

// ---------------- serial recurrence: one WG (1024 thr, 16 waves) per chain ----
// c=tid>>7: 8 k-slices of 64 h-elements; g=tid&127: outputs 4g..4g+3.
// 96 weight-words in VGPR (24 uint4, fits 128-reg budget), 64 in LDS.
__global__ __launch_bounds__(1024) void rnn_fused(
    const unsigned* __restrict__ xp2,    // [B][T][256] half2 words
    const unsigned* __restrict__ wpack,
    const unsigned* __restrict__ wldsg,
    const float* __restrict__ fcw, const float* __restrict__ fcb,
    float* __restrict__ out)
{
    __shared__ __align__(16) unsigned wlds[32768];   // 128 KB weight (LDS part)
    __shared__ __align__(16) float part[8 * 512];    // 16 KB partials
    __shared__ __align__(16) unsigned h2buf[256];    // 1 KB h (half2)
    __shared__ float wsum[4];

    const int tid = threadIdx.x;
    const int b = blockIdx.x;
    const int c = tid >> 7, g = tid & 127;

    {   // stage LDS weights: 8192 uint4 / 1024 thr = 8 each, coalesced
        const uint4* src = (const uint4*)wldsg;
        uint4* dst = (uint4*)wlds;
        #pragma unroll
        for (int q = 0; q < 8; ++q) dst[tid + (q << 10)] = src[tid + (q << 10)];
    }
    uint4 wr[4][6];                       // 96 VGPRs of packed half2
    {
        const uint4* wp4 = ((const uint4*)wpack) + tid;
        #pragma unroll
        for (int r = 0; r < 4; ++r)
            #pragma unroll
            for (int q = 0; q < 6; ++q)
                wr[r][q] = wp4[(r * 6 + q) << 10];
    }
    if (tid < 256) h2buf[tid] = 0u;
    __syncthreads();

    const unsigned* xpb = xp2 + (size_t)b * T_ * 256;
    const uint4* hv  = ((const uint4*)h2buf) + (c << 3);      // wave-uniform
    const uint4* wqp = ((const uint4*)wlds) + (c << 10) + g;  // imm-offset safe
    float4* pw = ((float4*)part) + (c << 7) + g;
    const float2* p2 = (const float2*)part;

    unsigned xpw = (tid < 256) ? xpb[tid] : 0u;               // xp[0]

    for (int t = 0; t < T_; ++t) {
        // prefetch xp[t+1] (at t=1023 reads 1 row past xp2 = start of wpack:
        // valid ws memory, value never consumed)
        unsigned xpn = (tid < 256) ? xpb[(t + 1) * 256 + tid] : 0u;

        float a0 = 0.f, a1 = 0.f, a2 = 0.f, a3 = 0.f;
        // register-resident weights: 6 uniform b128 h-reads, 96 fdot2
        #pragma unroll
        for (int q = 0; q < 6; ++q) {
            const uint4 hh = hv[q];
            a0 = fdot2u(wr[0][q].x, hh.x, a0); a1 = fdot2u(wr[1][q].x, hh.x, a1);
            a2 = fdot2u(wr[2][q].x, hh.x, a2); a3 = fdot2u(wr[3][q].x, hh.x, a3);
            a0 = fdot2u(wr[0][q].y, hh.y, a0); a1 = fdot2u(wr[1][q].y, hh.y, a1);
            a2 = fdot2u(wr[2][q].y, hh.y, a2); a3 = fdot2u(wr[3][q].y, hh.y, a3);
            a0 = fdot2u(wr[0][q].z, hh.z, a0); a1 = fdot2u(wr[1][q].z, hh.z, a1);
            a2 = fdot2u(wr[2][q].z, hh.z, a2); a3 = fdot2u(wr[3][q].z, hh.z, a3);
            a0 = fdot2u(wr[0][q].w, hh.w, a0); a1 = fdot2u(wr[1][q].w, hh.w, a1);
            a2 = fdot2u(wr[2][q].w, hh.w, a2); a3 = fdot2u(wr[3][q].w, hh.w, a3);
        }
        // LDS-resident weights: 2 uniform b128 h-reads + 8 coalesced b128
        #pragma unroll
        for (int q = 0; q < 2; ++q) {
            const uint4 hh = hv[6 + q];
            {   const uint4 w0 = wqp[(q * 4 + 0) * 128];
                a0 = fdot2u(w0.x, hh.x, a0); a1 = fdot2u(w0.y, hh.x, a1);
                a2 = fdot2u(w0.z, hh.x, a2); a3 = fdot2u(w0.w, hh.x, a3); }
            {   const uint4 w1 = wqp[(q * 4 + 1) * 128];
                a0 = fdot2u(w1.x, hh.y, a0); a1 = fdot2u(w1.y, hh.y, a1);
                a2 = fdot2u(w1.z, hh.y, a2); a3 = fdot2u(w1.w, hh.y, a3); }
            {   const uint4 w2v = wqp[(q * 4 + 2) * 128];
                a0 = fdot2u(w2v.x, hh.z, a0); a1 = fdot2u(w2v.y, hh.z, a1);
                a2 = fdot2u(w2v.z, hh.z, a2); a3 = fdot2u(w2v.w, hh.z, a3); }
            {   const uint4 w3 = wqp[(q * 4 + 3) * 128];
                a0 = fdot2u(w3.x, hh.w, a0); a1 = fdot2u(w3.y, hh.w, a1);
                a2 = fdot2u(w3.z, hh.w, a2); a3 = fdot2u(w3.w, hh.w, a3); }
        }
        *pw = make_float4(a0, a1, a2, a3);
        __syncthreads();                         // partials ready

        if (tid < 256) {                         // 4 of 16 waves: reduce + tanh
            float sx = 0.f, sy = 0.f;
            #pragma unroll
            for (int cc = 0; cc < 8; ++cc) {
                const float2 s = p2[(cc << 8) + tid];
                sx += s.x; sy += s.y;
            }
            U32H2 xu; xu.u = xpw;
            float pre0 = (float)xu.h.x + sx;
            float pre1 = (float)xu.h.y + sy;
            float e0 = __expf(2.0f * pre0), e1 = __expf(2.0f * pre1);
            float h0 = 1.0f - 2.0f / (e0 + 1.0f);
            float h1 = 1.0f - 2.0f / (e1 + 1.0f);
            h2buf[tid] = packh2(h0, h1);
        }
        xpw = xpn;
        __syncthreads();                         // h ready
    }

    // head: out[b] = dot(h, fc_w) + fc_b
    float p = 0.f;
    if (tid < 256) {
        U32H2 hu; hu.u = h2buf[tid];
        p = (float)hu.h.x * fcw[tid << 1] + (float)hu.h.y * fcw[(tid << 1) + 1];
    }
    #pragma unroll
    for (int off = 32; off >= 1; off >>= 1) p += __shfl_down(p, off, 64);
    if ((tid & 63) == 0 && tid < 256) wsum[tid >> 6] = p;
    __syncthreads();
    if (tid == 0) out[b] = wsum[0] + wsum[1] + wsum[2] + wsum[3] + fcb[0];
}

extern "C" void kernel_launch(void* const* d_in, const int* in_sizes, int n_in,
                              void* d_out, int out_size, void* d_ws, size_t ws_size,
                              hipStream_t stream) {
    const float* x   = (const float*)d_in[0];
    const float* wih = (const float*)d_in[1];
    const float* whh = (const float*)d_in[2];
    const float* bih = (const float*)d_in[3];
    const float* bhh = (const float*)d_in[4];
    const float* fcw = (const float*)d_in[5];
    const float* fcb = (const float*)d_in[6];
    float* out = (float*)d_out;

    // workspace (u32 units): xp2 | wpack | wldsg | wih2 | biasv  (~64.6 MiB)
    unsigned* xp2   = (unsigned*)d_ws;            // 64*1024*256
    unsigned* wpack = xp2 + 16777216;             // 98,304
    unsigned* wldsg = wpack + 98304;              // 32,768
    unsigned* wih2  = wldsg + 32768;              // 32,768
    float*    biasv = (float*)(wih2 + 32768);     // 512

    hipLaunchKernelGGL(prep, dim3(384), dim3(256), 0, stream,
                       wih, whh, bih, bhh, wpack, wldsg, wih2, biasv);
    hipLaunchKernelGGL(xp_gemm, dim3(B_, 32), dim3(512), 0, stream,
                       x, wih2, biasv, (_Float16*)xp2);
    hipLaunchKernelGGL(rnn_fused, dim3(B_), dim3(1024), 0, stream,
                       xp2, wpack, wldsg, fcw, fcb, out);
}